// Round 6
// baseline (761.138 us; speedup 1.0000x reference)
//
#include <hip/hip_runtime.h>

namespace {
constexpr int BATCH = 8;
constexpr int WIDTH = 48;
constexpr int N = WIDTH * WIDTH;   // 2304
// PW=56: row stride mod 32 = 24; tile-row stride 3*56 mod 32 = 8. A wave's 4
// tile-row groups sit at bank offsets {0,8,16,24}; the 16-lane column set
// {3k mod 32} covers exactly one of each {b, b+16} bank pair, so every conv
// read/write is a uniform 2-lanes-per-bank pattern (free on CDNA4).
constexpr int PW = 56;
constexpr int PH = 54;             // 48 + 6 halo
constexpr int NT = 512;            // 2 images/block: 8 waves -> 2 waves/SIMD
constexpr int NTH = 256;           // threads per image (3x3 tile each)
constexpr float EPS = 1e-8f;
constexpr int MAX_ITERS = 250;
constexpr float TOLSQ = 1e-10f;    // (1e-5)^2
}

__device__ __forceinline__ float wave_sum(float v) {
#pragma unroll
  for (int off = 32; off > 0; off >>= 1) v += __shfl_down(v, off);
  return v;
}

__device__ __forceinline__ float sum4(const float* buf) {
  const float4 a = *(const float4*)buf;  // broadcast b128, conflict-free
  return (a.x + a.y) + (a.z + a.w);
}

// Diamond (L1 radius 3) conv producing a 3x3 output tile (R3 structure: the
// compiler interleaves per-row loads with FMAs at 64 VGPRs). The 9 center
// values arrive in registers (c[]): 48 ds_reads per 9 outputs.
// SEL=0: weights (exp(-5d) - eps)      [K local part]
// SEL=1: weights d*(exp(-5d) - eps)    [K*cost local part; d=0 tap is zero]
template <int SEL>
__device__ __forceinline__ void conv_tile(const float* __restrict__ pad, int ip,
                                          const float* __restrict__ c,
                                          float* __restrict__ out) {
  float acc[9];
#pragma unroll
  for (int i = 0; i < 9; ++i) acc[i] = 0.f;
#pragma unroll
  for (int rho = -3; rho <= 5; ++rho) {   // input row relative to tile row 0
    const int drmin = (rho < 0) ? -rho : (rho > 2 ? rho - 2 : 0);
    const int w = 3 - drmin;              // widest halo any output row needs
    float rowv[9];
    const float* rp = pad + ip + rho * PW;
#pragma unroll
    for (int m = -w; m <= 2 + w; ++m) {
      if (rho >= 0 && rho <= 2 && m >= 0 && m <= 2)
        rowv[m + 3] = c[rho * 3 + m];
      else
        rowv[m + 3] = rp[m];
    }
#pragma unroll
    for (int r = 0; r < 3; ++r) {
      int d = rho - r; d = d < 0 ? -d : d;
      if (d > 3) continue;
#pragma unroll
      for (int k = 0; k < 3; ++k) {
#pragma unroll
        for (int m = -3; m <= 3; ++m) {
          if (m < -(3 - d) || m > (3 - d)) continue;
          const int dist = d + (m < 0 ? -m : m);
          float wgt;
          if (SEL == 0) {
            wgt = (dist == 0) ? 1.0f            // 1 - 1e-8 rounds to 1.0f
                : (dist == 1) ? 6.7379370e-3f   // exp(-5)  - 1e-8
                : (dist == 2) ? 4.5389930e-5f   // exp(-10) - 1e-8
                              : 2.9590232e-7f;  // exp(-15) - 1e-8
          } else {
            if (dist == 0) continue;
            wgt = (dist == 1) ? 6.7379370e-3f
                : (dist == 2) ? 9.0779860e-5f   // 2*(exp(-10) - 1e-8)
                              : 8.8770696e-7f;  // 3*(exp(-15) - 1e-8)
          }
          acc[r * 3 + k] += wgt * rowv[k + m + 3];
        }
      }
    }
  }
#pragma unroll
  for (int i = 0; i < 9; ++i) out[i] = acc[i];
}

__global__ __launch_bounds__(NT, 1) void sinkhorn48(const float* __restrict__ x,
                                                    const float* __restrict__ y,
                                                    float* __restrict__ out) {
  __shared__ float upad[2][PH * PW];
  __shared__ float vpad[2][PH * PW];
  __shared__ alignas(16) float rA[8];  // per half: Su partials / x-sum / dist
  __shared__ alignas(16) float rB[8];  // per half: Sv partials / y-sum
  __shared__ alignas(16) float rC[8];  // per half: diff^2 partials
  __shared__ float vrm[2][WIDTH];
  __shared__ float vcm[2][WIDTH];

  const int tid = threadIdx.x;
  const int half = tid >> 8;          // which of the block's 2 images
  const int st = tid & 255;           // sub-thread id within the image
  const int b = blockIdx.x * 2 + half;
  float* const up = upad[half];
  float* const vp = vpad[half];
  float* const myrA = rA + 4 * half;
  float* const myrB = rB + 4 * half;
  float* const myrC = rC + 4 * half;

  const int r0 = (st >> 4) * 3;       // 16 row-groups of 3 rows
  const int c0 = (st & 15) * 3;       // 16 col-groups of 3 cols
  const int ip = (r0 + 3) * PW + (c0 + 3);
  const int wid = (tid >> 6) & 3;     // wave index within this half
  const int lane = tid & 63;

  // Zero halos (and interiors) of this half's padded grids.
  for (int i = st; i < PH * PW; i += NTH) { up[i] = 0.f; vp[i] = 0.f; }

  // Load this thread's 3x3 pixels of both images into registers.
  const float* xb = x + b * N;
  const float* yb = y + b * N;
  float xr[9], yr[9];
#pragma unroll
  for (int r = 0; r < 3; ++r)
#pragma unroll
    for (int k = 0; k < 3; ++k) {
      xr[r * 3 + k] = xb[(r0 + r) * WIDTH + c0 + k];
      yr[r * 3 + k] = yb[(r0 + r) * WIDTH + c0 + k];
    }
  {
    float sx = 0.f, sy = 0.f;
#pragma unroll
    for (int i = 0; i < 9; ++i) { sx += xr[i]; sy += yr[i]; }
    sx = wave_sum(sx); sy = wave_sum(sy);
    if (lane == 0) { myrA[wid] = sx; myrB[wid] = sy; }
  }
  __syncthreads();  // B0: publishes rA/rB partials + zeroed pads
  const float irx = __builtin_amdgcn_rcpf(sum4(myrA));
  const float iry = __builtin_amdgcn_rcpf(sum4(myrB));
#pragma unroll
  for (int i = 0; i < 9; ++i) { xr[i] *= irx; yr[i] *= iry; }

  float ur[9];
#pragma unroll
  for (int i = 0; i < 9; ++i) ur[i] = 1.0f / (float)N;
#pragma unroll
  for (int r = 0; r < 3; ++r)
#pragma unroll
    for (int k = 0; k < 3; ++k) up[ip + r * PW + k] = ur[r * 3 + k];
  __syncthreads();  // B1: separates rA/rB reads above from rewrite below
  if (st < 4) { myrA[st] = 0.25f; myrC[st] = 1.0f; }  // Su(u0)=1; dummy diff
  __syncthreads();  // B2: publishes rA/rC + upad interior

  float cc[9], vv[9];
  bool done = false;                   // this half frozen (reference semantics)
  for (int iter = 0; iter < MAX_ITERS; ++iter) {
    // Exit/freeze bookkeeping: both halves' diff^2 from partials published at
    // the last barrier. Broadcast b128 reads, uniform across the block.
    const float dA = sum4(rC);
    const float dB = sum4(rC + 4);
    // Reference freezes u at the first i>0 with diff<TOL; our dsq is from
    // ref index i=iter-1, so gate at iter>=2. A frozen half stops writing
    // rC, so its dsq stays < TOL (latch holds).
    if (iter >= 2) {
      const float myd = half ? dB : dA;
      done = done || (myd < TOLSQ);
      if (dA < TOLSQ && dB < TOLSQ) break;  // block-uniform exit
    }
    if (!done) {
      const float Su = sum4(myrA);  // published at last barrier; hides in conv
      conv_tile<0>(up, ip, ur, cc);
      const float base = EPS * Su;
      float pv = 0.f;
#pragma unroll
      for (int i = 0; i < 9; ++i) {
        vv[i] = yr[i] * __builtin_amdgcn_rcpf(base + cc[i]);
        pv += vv[i];
      }
#pragma unroll
      for (int r = 0; r < 3; ++r)
#pragma unroll
        for (int k = 0; k < 3; ++k) vp[ip + r * PW + k] = vv[r * 3 + k];
      pv = wave_sum(pv);
      if (lane == 0) myrB[wid] = pv;
    }
    __syncthreads();  // A: publishes vpad + Sv partials

    if (!done) {
      const float Sv = sum4(myrB);  // hides behind conv(vpad)
      conv_tile<0>(vp, ip, vv, cc);
      const float base2 = EPS * Sv;
      float psu = 0.f, pd = 0.f;
#pragma unroll
      for (int i = 0; i < 9; ++i) {
        const float un = xr[i] * __builtin_amdgcn_rcpf(base2 + cc[i]);
        const float d = ur[i] - un;
        ur[i] = un;
        psu += un;
        pd += d * d;
      }
#pragma unroll
      for (int r = 0; r < 3; ++r)
#pragma unroll
        for (int k = 0; k < 3; ++k) up[ip + r * PW + k] = ur[r * 3 + k];
      psu = wave_sum(psu);
      pd = wave_sum(pd);
      if (lane == 0) { myrA[wid] = psu; myrC[wid] = pd; }
    }
    __syncthreads();  // B: publishes upad + Su/diff partials
  }

  // Final v from this half's (frozen) u. rA partials match upad on all paths.
  const float SuF = sum4(myrA);
  conv_tile<0>(up, ip, ur, cc);
  const float base = EPS * SuF;
#pragma unroll
  for (int i = 0; i < 9; ++i) vv[i] = yr[i] * __builtin_amdgcn_rcpf(base + cc[i]);
#pragma unroll
  for (int r = 0; r < 3; ++r)
#pragma unroll
    for (int k = 0; k < 3; ++k) vp[ip + r * PW + k] = vv[r * 3 + k];
  __syncthreads();

  // Row/col marginals of v for the separable eps*(C @ v) term (one-time).
  if (st < WIDTH) {
    float s = 0.f;
    const float* rp = vp + (st + 3) * PW + 3;
    for (int c = 0; c < WIDTH; ++c) s += rp[c];
    vrm[half][st] = s;
  } else if (st >= 64 && st < 64 + WIDTH) {
    const int c = st - 64;
    float s = 0.f;
    const float* cp = vp + 3 * PW + 3 + c;
    for (int r = 0; r < WIDTH; ++r) s += cp[r * PW];
    vcm[half][c] = s;
  }
  __syncthreads();

  // dist_b = sum_j u_j * ( eps*(Cv)_j + distance-weighted local conv )
  float aD[9];
  conv_tile<1>(vp, ip, vv, aD);
  float part = 0.f;
#pragma unroll
  for (int r = 0; r < 3; ++r) {
    const int rr = r0 + r;
    float cvr = 0.f;
    for (int q = 0; q < WIDTH; ++q) cvr += vrm[half][q] * fabsf((float)(q - rr));
#pragma unroll
    for (int k = 0; k < 3; ++k) {
      const int ccol = c0 + k;
      float cvc = 0.f;
      for (int q = 0; q < WIDTH; ++q) cvc += vcm[half][q] * fabsf((float)(q - ccol));
      part += ur[r * 3 + k] * (EPS * (cvr + cvc) + aD[r * 3 + k]);
    }
  }
  {
    const float p = wave_sum(part);
    if (lane == 0) myrA[wid] = p;  // WAR on rA separated by the barriers above
  }
  __syncthreads();
  if (st == 0) out[b] = sum4(myrA);
}

extern "C" void kernel_launch(void* const* d_in, const int* in_sizes, int n_in,
                              void* d_out, int out_size, void* d_ws, size_t ws_size,
                              hipStream_t stream) {
  const float* x = (const float*)d_in[0];
  const float* y = (const float*)d_in[1];
  float* out = (float*)d_out;
  sinkhorn48<<<BATCH / 2, NT, 0, stream>>>(x, y, out);
}

// Round 7
// 544.728 us; speedup vs baseline: 1.3973x; 1.3973x over previous
//
#include <hip/hip_runtime.h>

namespace {
constexpr int BATCH = 8;
constexpr int WIDTH = 48;
constexpr int N = WIDTH * WIDTH;   // 2304
// PW=56: row stride mod 32 = 24; tile-row stride 3*56 mod 32 = 8. A wave's 4
// tile-row groups sit at bank offsets {0,8,16,24}; the 16-lane column set
// {3k mod 32} covers exactly one of each {b, b+16} bank pair -> uniform
// 2-lanes-per-bank (free on CDNA4).
constexpr int PW = 56;
constexpr int PH = 54;             // 48 + 6 halo
constexpr int NT = 256;            // 4 waves; each thread owns a 3x3 pixel tile
constexpr int NWAVE = NT / 64;
constexpr float EPS = 1e-8f;
constexpr int MAX_ITERS = 250;
constexpr float TOLSQ = 1e-10f;    // (1e-5)^2
}

// DPP lane shifts within each 16-lane row; bound_ctrl=true zero-fills at the
// row boundary, which coincides exactly with the grid's column edge (16
// col-groups per grid row), reproducing the zero halo.
__device__ __forceinline__ float dpp_shr1(float v) {  // lane n <- lane n-1
  return __int_as_float(__builtin_amdgcn_update_dpp(
      0, __float_as_int(v), 0x111, 0xf, 0xf, true));
}
__device__ __forceinline__ float dpp_shl1(float v) {  // lane n <- lane n+1
  return __int_as_float(__builtin_amdgcn_update_dpp(
      0, __float_as_int(v), 0x101, 0xf, 0xf, true));
}

__device__ __forceinline__ float wave_sum(float v) {
#pragma unroll
  for (int off = 32; off > 0; off >>= 1) v += __shfl_down(v, off);
  return v;
}

__device__ __forceinline__ float sum4(const float* buf) {
  const float4 a = *(const float4*)buf;  // broadcast b128, conflict-free
  return (a.x + a.y) + (a.z + a.w);
}

// Diamond (L1 radius 3) conv producing a 3x3 output tile. Same-row halo
// (18 cells) comes from neighbor lanes' registers via DPP (VALU pipe, no
// LDS); only the 30 vertical-halo cells (spans 3,5,7 above and below) are
// read from LDS. Centers arrive in registers (c[]).
// SEL=0: weights (exp(-5d) - eps)      [K local part]
// SEL=1: weights d*(exp(-5d) - eps)    [K*cost local part; d=0 tap is zero]
template <int SEL>
__device__ __forceinline__ void conv_tile(const float* __restrict__ pad, int ip,
                                          const float* __restrict__ c,
                                          float* __restrict__ out) {
  float hl[9], hr[9];
#pragma unroll
  for (int i = 0; i < 9; ++i) {
    hl[i] = dpp_shr1(c[i]);  // cols c0-3..c0-1 (left neighbor's tile)
    hr[i] = dpp_shl1(c[i]);  // cols c0+3..c0+5 (right neighbor's tile)
  }
  float acc[9];
#pragma unroll
  for (int i = 0; i < 9; ++i) acc[i] = 0.f;
#pragma unroll
  for (int rho = -3; rho <= 5; ++rho) {   // input row relative to tile row 0
    const int drmin = (rho < 0) ? -rho : (rho > 2 ? rho - 2 : 0);
    const int w = 3 - drmin;              // widest halo any output row needs
    float rowv[9];                        // rowv[m+3] = cell at col c0+m
    if (rho >= 0 && rho <= 2) {
#pragma unroll
      for (int k = 0; k < 3; ++k) {
        rowv[k] = hl[rho * 3 + k];
        rowv[3 + k] = c[rho * 3 + k];
        rowv[6 + k] = hr[rho * 3 + k];
      }
    } else {
      const float* rp = pad + ip + rho * PW;
#pragma unroll
      for (int m = -w; m <= 2 + w; ++m) rowv[m + 3] = rp[m];
    }
#pragma unroll
    for (int r = 0; r < 3; ++r) {
      int d = rho - r; d = d < 0 ? -d : d;
      if (d > 3) continue;
#pragma unroll
      for (int k = 0; k < 3; ++k) {
#pragma unroll
        for (int m = -3; m <= 3; ++m) {
          if (m < -(3 - d) || m > (3 - d)) continue;
          const int dist = d + (m < 0 ? -m : m);
          float wgt;
          if (SEL == 0) {
            wgt = (dist == 0) ? 1.0f            // 1 - 1e-8 rounds to 1.0f
                : (dist == 1) ? 6.7379370e-3f   // exp(-5)  - 1e-8
                : (dist == 2) ? 4.5389930e-5f   // exp(-10) - 1e-8
                              : 2.9590232e-7f;  // exp(-15) - 1e-8
          } else {
            if (dist == 0) continue;
            wgt = (dist == 1) ? 6.7379370e-3f
                : (dist == 2) ? 9.0779860e-5f   // 2*(exp(-10) - 1e-8)
                              : 8.8770696e-7f;  // 3*(exp(-15) - 1e-8)
          }
          acc[r * 3 + k] += wgt * rowv[k + m + 3];
        }
      }
    }
  }
#pragma unroll
  for (int i = 0; i < 9; ++i) out[i] = acc[i];
}

__global__ __launch_bounds__(NT, 1) void sinkhorn48(const float* __restrict__ x,
                                                    const float* __restrict__ y,
                                                    float* __restrict__ out) {
  __shared__ float upad[PH * PW];
  __shared__ float vpad[PH * PW];
  __shared__ alignas(16) float rA[4];  // Su partials / x-sum / dist partials
  __shared__ alignas(16) float rB[4];  // Sv partials / y-sum
  __shared__ alignas(16) float rC[4];  // diff^2 partials
  __shared__ float vr[WIDTH];
  __shared__ float vc[WIDTH];

  const int tid = threadIdx.x;
  const int b = blockIdx.x;
  const int r0 = (tid >> 4) * 3;      // 16 row-groups of 3 rows
  const int c0 = (tid & 15) * 3;      // 16 col-groups of 3 cols
  const int ip = (r0 + 3) * PW + (c0 + 3);
  const int wid = tid >> 6;
  const int lane = tid & 63;

  // Zero halos (and interiors) of the padded grids.
  for (int i = tid; i < PH * PW; i += NT) { upad[i] = 0.f; vpad[i] = 0.f; }

  // Load this thread's 3x3 pixels of both images into registers.
  const float* xb = x + b * N;
  const float* yb = y + b * N;
  float xr[9], yr[9];
#pragma unroll
  for (int r = 0; r < 3; ++r)
#pragma unroll
    for (int k = 0; k < 3; ++k) {
      xr[r * 3 + k] = xb[(r0 + r) * WIDTH + c0 + k];
      yr[r * 3 + k] = yb[(r0 + r) * WIDTH + c0 + k];
    }
  {
    float sx = 0.f, sy = 0.f;
#pragma unroll
    for (int i = 0; i < 9; ++i) { sx += xr[i]; sy += yr[i]; }
    sx = wave_sum(sx); sy = wave_sum(sy);
    if (lane == 0) { rA[wid] = sx; rB[wid] = sy; }
  }
  __syncthreads();  // B0: publishes rA/rB partials + zeroed pads
  const float irx = __builtin_amdgcn_rcpf(sum4(rA));
  const float iry = __builtin_amdgcn_rcpf(sum4(rB));
#pragma unroll
  for (int i = 0; i < 9; ++i) { xr[i] *= irx; yr[i] *= iry; }

  float ur[9];
#pragma unroll
  for (int i = 0; i < 9; ++i) ur[i] = 1.0f / (float)N;
#pragma unroll
  for (int r = 0; r < 3; ++r)
#pragma unroll
    for (int k = 0; k < 3; ++k) upad[ip + r * PW + k] = ur[r * 3 + k];
  __syncthreads();  // B1: separates rA/rB reads above from rewrite below
  if (tid < NWAVE) { rA[tid] = 1.0f / (float)NWAVE; rC[tid] = 1.0f; }
  __syncthreads();  // B2: publishes rA (Su(u0)=1), rC dummy, upad interior

  float cc[9], vv[9];
  for (int iter = 0; iter < MAX_ITERS; ++iter) {
    // Partial sums published at the last barrier; independent of the conv, so
    // their read latency hides behind it.
    const float Su = sum4(rA);
    const float dsq = sum4(rC);
    conv_tile<0>(upad, ip, ur, cc);
    // Reference freezes u at the first i>0 with diff<TOL; dsq here is from
    // iteration (iter-1). Break before any state write -> exact match.
    if (iter >= 2 && dsq < TOLSQ) break;
    const float base = EPS * Su;
    float pv = 0.f;
#pragma unroll
    for (int i = 0; i < 9; ++i) {
      vv[i] = yr[i] * __builtin_amdgcn_rcpf(base + cc[i]);
      pv += vv[i];
    }
#pragma unroll
    for (int r = 0; r < 3; ++r)
#pragma unroll
      for (int k = 0; k < 3; ++k) vpad[ip + r * PW + k] = vv[r * 3 + k];
    pv = wave_sum(pv);
    if (lane == 0) rB[wid] = pv;
    __syncthreads();  // A: publishes vpad + Sv partials

    const float Sv = sum4(rB);  // hides behind conv(vpad)
    conv_tile<0>(vpad, ip, vv, cc);
    const float base2 = EPS * Sv;
    float psu = 0.f, pd = 0.f;
#pragma unroll
    for (int i = 0; i < 9; ++i) {
      const float un = xr[i] * __builtin_amdgcn_rcpf(base2 + cc[i]);
      const float d = ur[i] - un;
      ur[i] = un;
      psu += un;
      pd += d * d;
    }
#pragma unroll
    for (int r = 0; r < 3; ++r)
#pragma unroll
      for (int k = 0; k < 3; ++k) upad[ip + r * PW + k] = ur[r * 3 + k];
    psu = wave_sum(psu);
    pd = wave_sum(pd);
    if (lane == 0) { rA[wid] = psu; rC[wid] = pd; }
    __syncthreads();  // B: publishes upad + Su/diff partials
  }

  // Final v from converged u. rA partials match current upad on both exit paths.
  const float SuF = sum4(rA);
  conv_tile<0>(upad, ip, ur, cc);
  const float base = EPS * SuF;
#pragma unroll
  for (int i = 0; i < 9; ++i) vv[i] = yr[i] * __builtin_amdgcn_rcpf(base + cc[i]);
#pragma unroll
  for (int r = 0; r < 3; ++r)
#pragma unroll
    for (int k = 0; k < 3; ++k) vpad[ip + r * PW + k] = vv[r * 3 + k];
  __syncthreads();

  // Row/col marginals of v for the separable eps*(C @ v) term (one-time).
  if (tid < WIDTH) {
    float s = 0.f;
    const float* rp = vpad + (tid + 3) * PW + 3;
    for (int c = 0; c < WIDTH; ++c) s += rp[c];
    vr[tid] = s;
  } else if (tid >= 64 && tid < 64 + WIDTH) {
    const int c = tid - 64;
    float s = 0.f;
    const float* cp = vpad + 3 * PW + 3 + c;
    for (int r = 0; r < WIDTH; ++r) s += cp[r * PW];
    vc[c] = s;
  }
  __syncthreads();

  // dist_b = sum_j u_j * ( eps*(Cv)_j + distance-weighted local conv )
  float aD[9];
  conv_tile<1>(vpad, ip, vv, aD);
  float part = 0.f;
#pragma unroll
  for (int r = 0; r < 3; ++r) {
    const int rr = r0 + r;
    float cvr = 0.f;
    for (int q = 0; q < WIDTH; ++q) cvr += vr[q] * fabsf((float)(q - rr));
#pragma unroll
    for (int k = 0; k < 3; ++k) {
      const int ccol = c0 + k;
      float cvc = 0.f;
      for (int q = 0; q < WIDTH; ++q) cvc += vc[q] * fabsf((float)(q - ccol));
      part += ur[r * 3 + k] * (EPS * (cvr + cvc) + aD[r * 3 + k]);
    }
  }
  {
    const float p = wave_sum(part);
    if (lane == 0) rA[wid] = p;  // WAR on rA separated by the barriers above
  }
  __syncthreads();
  if (tid == 0) out[b] = sum4(rA);
}

extern "C" void kernel_launch(void* const* d_in, const int* in_sizes, int n_in,
                              void* d_out, int out_size, void* d_ws, size_t ws_size,
                              hipStream_t stream) {
  const float* x = (const float*)d_in[0];
  const float* y = (const float*)d_in[1];
  float* out = (float*)d_out;
  sinkhorn48<<<BATCH, NT, 0, stream>>>(x, y, out);
}